// Round 8
// baseline (1729.624 us; speedup 1.0000x reference)
//
#include <hip/hip_runtime.h>
#include <hip/hip_bf16.h>
#include <hip/hip_fp16.h>
#include <math.h>

#define DH 10      // hidden dim
#define DE 3       // edge attr dim
#define DIN 3      // input dim
#define REC 20     // fp32 D record: 20 floats = 80B
#define SHU 12     // fp16 S record stride in uints (24 halves = 48B, 10 used)
#define ACS 12     // acc stride in floats (48B, 16B-aligned)
#define VEC 4      // lanes cooperating per node in gather
#define NR 8       // src slices; slice S-records = 25k * 48B = 1.2MB (fits XCD L2)

typedef unsigned int u32;
typedef float f4v __attribute__((ext_vector_type(4)));   // native vec: OK for nontemporal builtins

__device__ __forceinline__ u32 pack_h2(float a, float b) {
    union { __half2 h; u32 u; } cv;
    cv.h = __floats2half2_rn(a, b);
    return cv.u;
}
__device__ __forceinline__ float2 unpack_h2(u32 u) {
    union { u32 u; __half2 h; } cv; cv.u = u;
    return __half22float2(cv.h);
}

// ---------------------------------------------------------------------------
// Per-node records. D (fp32, dst side, biases folded). S (fp16 packed).
// ---------------------------------------------------------------------------
__device__ __forceinline__ void compute_records_h(
    const float* __restrict__ hh,
    const float* __restrict__ fW, const float* __restrict__ fb,
    const float* __restrict__ sW, const float* __restrict__ sb,
    float* __restrict__ Dout, u32* __restrict__ Sout)
{
    float fsv[DH], ssv[DH];
#pragma unroll
    for (int j = 0; j < DH; ++j) {
        float fd = fb[j], sd = sb[j], fs = 0.f, ss = 0.f;
#pragma unroll
        for (int k = 0; k < DH; ++k) {
            fd += hh[k] * fW[j*23 + k];
            fs += hh[k] * fW[j*23 + 10 + k];
            sd += hh[k] * sW[j*23 + k];
            ss += hh[k] * sW[j*23 + 10 + k];
        }
        Dout[j]      = fd;
        Dout[DH + j] = sd;
        fsv[j] = fs;
        ssv[j] = ss;
    }
#pragma unroll
    for (int j = 0; j < 5; ++j) {
        Sout[j]     = pack_h2(fsv[2*j], fsv[2*j+1]);
        Sout[5 + j] = pack_h2(ssv[2*j], ssv[2*j+1]);
    }
}

// fp32 variant for the fallback path
__device__ __forceinline__ void compute_records(
    const float* __restrict__ hh,
    const float* __restrict__ fW, const float* __restrict__ fb,
    const float* __restrict__ sW, const float* __restrict__ sb,
    float* __restrict__ Dout, float* __restrict__ Sout)
{
#pragma unroll
    for (int j = 0; j < DH; ++j) {
        float fd = fb[j], sd = sb[j], fs = 0.f, ss = 0.f;
#pragma unroll
        for (int k = 0; k < DH; ++k) {
            fd += hh[k] * fW[j*23 + k];
            fs += hh[k] * fW[j*23 + 10 + k];
            sd += hh[k] * sW[j*23 + k];
            ss += hh[k] * sW[j*23 + 10 + k];
        }
        Dout[j]      = fd;
        Dout[DH + j] = sd;
        Sout[j]      = fs;
        Sout[DH + j] = ss;
    }
}

// ---------------------------------------------------------------------------
// zero deg table + pooling accumulators
// ---------------------------------------------------------------------------
__global__ void zero_misc(int* __restrict__ deg, int M,
                          float* __restrict__ gsum, float* __restrict__ gcnt, int G)
{
    int i = blockIdx.x * blockDim.x + threadIdx.x;
    if (i < M) deg[i] = 0;
    if (i < G * DH) gsum[i] = 0.f;
    if (i < G) gcnt[i] = 0.f;
}

// ---------------------------------------------------------------------------
// P0: h0 = relu(x@preW.T+preb); layer-1 records; zero acc
// ---------------------------------------------------------------------------
__global__ void node_pre_h(const float* __restrict__ x,
                           const float* __restrict__ preW, const float* __restrict__ preb,
                           const float* __restrict__ fW, const float* __restrict__ fb,
                           const float* __restrict__ sW, const float* __restrict__ sb,
                           float* __restrict__ h, float* __restrict__ D, u32* __restrict__ Sh,
                           float* __restrict__ acc, int N)
{
    __shared__ float lpW[30], lpb[10], lfW[230], lfb[10], lsW[230], lsb[10];
    for (int i = threadIdx.x; i < 30;  i += blockDim.x) lpW[i] = preW[i];
    for (int i = threadIdx.x; i < 10;  i += blockDim.x) { lpb[i] = preb[i]; lfb[i] = fb[i]; lsb[i] = sb[i]; }
    for (int i = threadIdx.x; i < 230; i += blockDim.x) { lfW[i] = fW[i]; lsW[i] = sW[i]; }
    __syncthreads();

    int n = blockIdx.x * blockDim.x + threadIdx.x;
    if (n >= N) return;

    float x0 = x[(size_t)n*3], x1 = x[(size_t)n*3+1], x2 = x[(size_t)n*3+2];
    float hh[DH];
#pragma unroll
    for (int j = 0; j < DH; ++j)
        hh[j] = fmaxf(lpb[j] + x0*lpW[j*3] + x1*lpW[j*3+1] + x2*lpW[j*3+2], 0.f);

    float* hp = h + (size_t)n * DH;
#pragma unroll
    for (int j = 0; j < DH; ++j) hp[j] = hh[j];
    float4* ap = (float4*)(acc + (size_t)n * ACS);
    ap[0] = make_float4(0,0,0,0); ap[1] = make_float4(0,0,0,0); ap[2] = make_float4(0,0,0,0);

    compute_records_h(hh, lfW, lfb, lsW, lsb, D + (size_t)n*REC, Sh + (size_t)n*SHU);
}

// ---------------------------------------------------------------------------
// CSR build (slice-major layout [r][n]): hist -> flat scan -> scatter (SoA)
// ---------------------------------------------------------------------------
__global__ void hist8(const int* __restrict__ ei, int* __restrict__ deg, int E, int RS, int N)
{
    int e = blockIdx.x * blockDim.x + threadIdx.x;
    if (e >= E) return;
    int src = __builtin_nontemporal_load(ei + e);
    int dst = __builtin_nontemporal_load(ei + (size_t)E + e);
    int r = src / RS;
    atomicAdd(&deg[(size_t)r * N + dst], 1);
}

__global__ void scan_block(const int* __restrict__ deg, int* __restrict__ excl,
                           int* __restrict__ bsum, int M)
{
    __shared__ int s[256];
    int tid = threadIdx.x;
    int i = blockIdx.x * 256 + tid;
    int v = (i < M) ? deg[i] : 0;
    s[tid] = v;
    __syncthreads();
#pragma unroll
    for (int off = 1; off < 256; off <<= 1) {
        int t = (tid >= off) ? s[tid - off] : 0;
        __syncthreads();
        if (tid >= off) s[tid] += t;
        __syncthreads();
    }
    if (i < M) excl[i] = s[tid] - v;
    if (tid == 255) bsum[blockIdx.x] = s[255];
}

__global__ void scan_sums_loop(int* __restrict__ bsum, int B)   // exclusive, in place
{
    __shared__ int s[1024];
    __shared__ int carry_s;
    int tid = threadIdx.x;
    if (tid == 0) carry_s = 0;
    __syncthreads();
    for (int base = 0; base < B; base += 1024) {
        int i = base + tid;
        int v = (i < B) ? bsum[i] : 0;
        s[tid] = v;
        __syncthreads();
#pragma unroll
        for (int off = 1; off < 1024; off <<= 1) {
            int t = (tid >= off) ? s[tid - off] : 0;
            __syncthreads();
            if (tid >= off) s[tid] += t;
            __syncthreads();
        }
        int carry = carry_s;
        if (i < B) bsum[i] = carry + s[tid] - v;
        __syncthreads();
        if (tid == 0) carry_s = carry + s[1023];
        __syncthreads();
    }
}

__global__ void scan_add(int* __restrict__ bhead, const int* __restrict__ bsum, int M)
{
    int i = blockIdx.x * blockDim.x + threadIdx.x;
    if (i < M) bhead[i] += bsum[i >> 8];
}

__global__ void scatter8(const int* __restrict__ ei, const float* __restrict__ attr,
                         int* __restrict__ bhead, u32* __restrict__ csrc,
                         uint2* __restrict__ cattr, int E, int RS, int N)
{
    int e = blockIdx.x * blockDim.x + threadIdx.x;
    if (e >= E) return;
    int src = __builtin_nontemporal_load(ei + e);
    int dst = __builtin_nontemporal_load(ei + (size_t)E + e);
    float a0 = __builtin_nontemporal_load(attr + (size_t)e * DE);
    float a1 = __builtin_nontemporal_load(attr + (size_t)e * DE + 1);
    float a2 = __builtin_nontemporal_load(attr + (size_t)e * DE + 2);
    int r = src / RS;
    int pos = atomicAdd(&bhead[(size_t)r * N + dst], 1);
    csrc[pos]  = (u32)src;
    cattr[pos] = make_uint2(pack_h2(a0, a1), pack_h2(a2, 0.f));
}

// ---------------------------------------------------------------------------
// Gather for ONE src-slice p. All waves touch only slice p's S-records
// (1.2MB -> L2-resident). acc += partial (RMW; dispatches are stream-ordered).
// ---------------------------------------------------------------------------
__global__ __launch_bounds__(256) void gather_slice(
    int p, const int* __restrict__ deg, const int* __restrict__ bhead,
    const u32* __restrict__ csrc, const uint2* __restrict__ cattr,
    const float* __restrict__ D, const u32* __restrict__ ShU,
    const float* __restrict__ Wf, const float* __restrict__ Ws,
    float* __restrict__ acc, int N)
{
    float wf[30], wsr[30];
#pragma unroll
    for (int i = 0; i < 30; ++i) {
        int j = i / 3, t = i % 3;
        wf[i]  = Wf[j*23 + 20 + t];
        wsr[i] = Ws[j*23 + 20 + t];
    }

    int tid = blockIdx.x * blockDim.x + threadIdx.x;
    int n   = tid >> 2;
    int sub = tid & (VEC - 1);
    if (n >= N) return;

    size_t idx = (size_t)p * N + n;
    int end = bhead[idx];
    int cnt = deg[idx];
    int start = end - cnt;

    float partial[DH];
#pragma unroll
    for (int j = 0; j < DH; ++j) partial[j] = 0.f;

    if (cnt > 0) {
        float drec[REC];
        const f4v* Dp = (const f4v*)(D + (size_t)n * REC);
#pragma unroll
        for (int i = 0; i < 5; ++i) {
            f4v v = __builtin_nontemporal_load(Dp + i);
            ((f4v*)drec)[i] = v;
        }

        for (int q = start + sub; q < end; q += VEC) {
            u32  src = __builtin_nontemporal_load(csrc + q);
            uint2 at; // 8B attr, nontemporal
            at.x = __builtin_nontemporal_load(&cattr[q].x);
            at.y = __builtin_nontemporal_load(&cattr[q].y);
            float2 a01 = unpack_h2(at.x);
            float2 a2_ = unpack_h2(at.y);
            float a0 = a01.x, a1 = a01.y, a2 = a2_.x;

            // srec: plain loads -> cached in slice-resident L2
            const uint4* sp = (const uint4*)(ShU + (size_t)src * SHU);
            uint4 A = sp[0];
            uint4 B = sp[1];
            uint2 C = *(const uint2*)(sp + 2);
            u32 u[10] = {A.x, A.y, A.z, A.w, B.x, B.y, B.z, B.w, C.x, C.y};
            float s[20];
#pragma unroll
            for (int i = 0; i < 10; ++i) {
                float2 f = unpack_h2(u[i]);
                s[2*i] = f.x; s[2*i+1] = f.y;
            }
#pragma unroll
            for (int j = 0; j < DH; ++j) {
                float pf = drec[j]      + s[j]      + a0*wf[j*3]  + a1*wf[j*3+1]  + a2*wf[j*3+2];
                float ps = drec[DH + j] + s[DH + j] + a0*wsr[j*3] + a1*wsr[j*3+1] + a2*wsr[j*3+2];
                float sg = __builtin_amdgcn_rcpf(1.0f + __expf(-pf));          // sigmoid
                float sp2 = fmaxf(ps, 0.f) + __logf(1.0f + __expf(-fabsf(ps))); // softplus
                partial[j] += sg * sp2;
            }
        }
    }

    // butterfly reduce across the 4 lanes of this node
#pragma unroll
    for (int j = 0; j < DH; ++j) {
        partial[j] += __shfl_xor(partial[j], 1);
        partial[j] += __shfl_xor(partial[j], 2);
    }

    if (sub == 0 && cnt > 0) {
        float* ap = acc + (size_t)n * ACS;
        float4 a0v = ((float4*)ap)[0];
        float4 a1v = ((float4*)ap)[1];
        float2 a2v = ((float2*)ap)[4];
        a0v.x += partial[0]; a0v.y += partial[1]; a0v.z += partial[2]; a0v.w += partial[3];
        a1v.x += partial[4]; a1v.y += partial[5]; a1v.z += partial[6]; a1v.w += partial[7];
        a2v.x += partial[8]; a2v.y += partial[9];
        ((float4*)ap)[0] = a0v;
        ((float4*)ap)[1] = a1v;
        ((float2*)ap)[4] = a2v;
    }
}

// ---------------------------------------------------------------------------
// Layer-1 epilogue: h = relu(h + acc); records for layer 2; re-zero acc
// ---------------------------------------------------------------------------
__global__ void node_mid_h(float* __restrict__ h, float* __restrict__ acc,
                           const float* __restrict__ fW, const float* __restrict__ fb,
                           const float* __restrict__ sW, const float* __restrict__ sb,
                           float* __restrict__ D, u32* __restrict__ Sh, int N)
{
    __shared__ float lfW[230], lfb[10], lsW[230], lsb[10];
    for (int i = threadIdx.x; i < 230; i += blockDim.x) { lfW[i] = fW[i]; lsW[i] = sW[i]; }
    for (int i = threadIdx.x; i < 10;  i += blockDim.x) { lfb[i] = fb[i]; lsb[i] = sb[i]; }
    __syncthreads();
    int n = blockIdx.x * blockDim.x + threadIdx.x;
    if (n >= N) return;
    float* hp = h + (size_t)n * DH;
    float* ap = acc + (size_t)n * ACS;
    float hh[DH];
#pragma unroll
    for (int j = 0; j < DH; ++j) {
        hh[j] = fmaxf(hp[j] + ap[j], 0.f);
        hp[j] = hh[j];
    }
    float4* apv = (float4*)ap;
    apv[0] = make_float4(0,0,0,0); apv[1] = make_float4(0,0,0,0); apv[2] = make_float4(0,0,0,0);
    compute_records_h(hh, lfW, lfb, lsW, lsb, D + (size_t)n*REC, Sh + (size_t)n*SHU);
}

// ---------------------------------------------------------------------------
// Layer-2 epilogue: pool relu(h + acc) into gsum/gcnt
// ---------------------------------------------------------------------------
__global__ void node_pool(const float* __restrict__ h, const float* __restrict__ acc,
                          const int* __restrict__ batch,
                          float* __restrict__ gsum, float* __restrict__ gcnt, int N)
{
    int n = blockIdx.x * blockDim.x + threadIdx.x;
    if (n >= N) return;
    int b = batch[n];
    const float* hp = h + (size_t)n * DH;
    const float* ap = acc + (size_t)n * ACS;
    float* gp = gsum + (size_t)b * DH;
#pragma unroll
    for (int j = 0; j < DH; ++j)
        atomicAdd(gp + j, fmaxf(hp[j] + ap[j], 0.f));
    atomicAdd(gcnt + b, 1.f);
}

// ---------------------------------------------------------------------------
// Fallback path kernels (fp32 atomic path; used only if ws too small)
// ---------------------------------------------------------------------------
__global__ void node_pre_f32(const float* __restrict__ x,
                             const float* __restrict__ preW, const float* __restrict__ preb,
                             const float* __restrict__ fW, const float* __restrict__ fb,
                             const float* __restrict__ sW, const float* __restrict__ sb,
                             float* __restrict__ h, float* __restrict__ D, float* __restrict__ S,
                             float* __restrict__ agg,
                             float* __restrict__ gsum, float* __restrict__ gcnt, int N, int G)
{
    __shared__ float lpW[30], lpb[10], lfW[230], lfb[10], lsW[230], lsb[10];
    for (int i = threadIdx.x; i < 30;  i += blockDim.x) lpW[i] = preW[i];
    for (int i = threadIdx.x; i < 10;  i += blockDim.x) { lpb[i] = preb[i]; lfb[i] = fb[i]; lsb[i] = sb[i]; }
    for (int i = threadIdx.x; i < 230; i += blockDim.x) { lfW[i] = fW[i]; lsW[i] = sW[i]; }
    __syncthreads();
    int n = blockIdx.x * blockDim.x + threadIdx.x;
    if (n < G * DH) gsum[n] = 0.f;
    if (n < G)      gcnt[n] = 0.f;
    if (n >= N) return;
    float x0 = x[(size_t)n*3], x1 = x[(size_t)n*3+1], x2 = x[(size_t)n*3+2];
    float hh[DH];
#pragma unroll
    for (int j = 0; j < DH; ++j)
        hh[j] = fmaxf(lpb[j] + x0*lpW[j*3] + x1*lpW[j*3+1] + x2*lpW[j*3+2], 0.f);
    float* hp = h + (size_t)n * DH;
    float* ap = agg + (size_t)n * DH;
#pragma unroll
    for (int j = 0; j < DH; ++j) { hp[j] = hh[j]; ap[j] = 0.f; }
    compute_records(hh, lfW, lfb, lsW, lsb, D + (size_t)n*REC, S + (size_t)n*REC);
}

__global__ void edge_pass(const int* __restrict__ ei, const float* __restrict__ attr,
                          const float* __restrict__ D, const float* __restrict__ S,
                          const float* __restrict__ Wf, const float* __restrict__ Ws,
                          float* __restrict__ agg, int E)
{
    __shared__ float wfe[30], wse[30];
    if (threadIdx.x < 30) {
        int j = threadIdx.x / 3, t = threadIdx.x % 3;
        wfe[threadIdx.x] = Wf[j*23 + 20 + t];
        wse[threadIdx.x] = Ws[j*23 + 20 + t];
    }
    __syncthreads();
    int e = blockIdx.x * blockDim.x + threadIdx.x;
    if (e >= E) return;
    int src = ei[e];
    int dst = ei[(size_t)E + e];
    const float* eap = attr + (size_t)e * DE;
    float ea0 = eap[0], ea1 = eap[1], ea2 = eap[2];
    float drec[REC], srec[REC];
    const float4* Dp = (const float4*)(D + (size_t)dst * REC);
    const float4* Sp = (const float4*)(S + (size_t)src * REC);
#pragma unroll
    for (int i = 0; i < 5; ++i) { ((float4*)drec)[i] = Dp[i]; ((float4*)srec)[i] = Sp[i]; }
    float* ap = agg + (size_t)dst * DH;
#pragma unroll
    for (int j = 0; j < DH; ++j) {
        float pf = drec[j]      + srec[j]      + ea0*wfe[j*3] + ea1*wfe[j*3+1] + ea2*wfe[j*3+2];
        float ps = drec[DH + j] + srec[DH + j] + ea0*wse[j*3] + ea1*wse[j*3+1] + ea2*wse[j*3+2];
        float sg = 1.0f / (1.0f + __expf(-pf));
        float sp = fmaxf(ps, 0.f) + log1pf(__expf(-fabsf(ps)));
        atomicAdd(ap + j, sg * sp);
    }
}

__global__ void node_mid(float* __restrict__ h, float* __restrict__ agg,
                         const float* __restrict__ fW, const float* __restrict__ fb,
                         const float* __restrict__ sW, const float* __restrict__ sb,
                         float* __restrict__ D, float* __restrict__ S, int N)
{
    __shared__ float lfW[230], lfb[10], lsW[230], lsb[10];
    for (int i = threadIdx.x; i < 230; i += blockDim.x) { lfW[i] = fW[i]; lsW[i] = sW[i]; }
    for (int i = threadIdx.x; i < 10;  i += blockDim.x) { lfb[i] = fb[i]; lsb[i] = sb[i]; }
    __syncthreads();
    int n = blockIdx.x * blockDim.x + threadIdx.x;
    if (n >= N) return;
    float* hp = h + (size_t)n * DH;
    float* ap = agg + (size_t)n * DH;
    float hh[DH];
#pragma unroll
    for (int j = 0; j < DH; ++j) {
        hh[j] = fmaxf(hp[j] + ap[j], 0.f);
        hp[j] = hh[j];
        ap[j] = 0.f;
    }
    compute_records(hh, lfW, lfb, lsW, lsb, D + (size_t)n*REC, S + (size_t)n*REC);
}

__global__ void node_post(const float* __restrict__ h, const float* __restrict__ agg,
                          const int* __restrict__ batch,
                          float* __restrict__ gsum, float* __restrict__ gcnt, int N)
{
    int n = blockIdx.x * blockDim.x + threadIdx.x;
    if (n >= N) return;
    int b = batch[n];
    const float* hp = h + (size_t)n * DH;
    const float* ap = agg + (size_t)n * DH;
    float* gp = gsum + (size_t)b * DH;
#pragma unroll
    for (int j = 0; j < DH; ++j)
        atomicAdd(gp + j, fmaxf(hp[j] + ap[j], 0.f));
    atomicAdd(gcnt + b, 1.f);
}

// ---------------------------------------------------------------------------
// MLP head: one block (128 threads) per graph.
// ---------------------------------------------------------------------------
__global__ void mlp_head(const float* __restrict__ gsum, const float* __restrict__ gcnt,
                         const float* __restrict__ fc1W, const float* __restrict__ fc1b,
                         const float* __restrict__ fc2W, const float* __restrict__ fc2b,
                         const float* __restrict__ outW, const float* __restrict__ outb,
                         float* __restrict__ out, int G)
{
    __shared__ float g[DH], a1[128], a2[128];
    int gid = blockIdx.x;
    int t = threadIdx.x;
    if (t < DH) {
        float c = fmaxf(gcnt[gid], 1.0f);
        g[t] = gsum[(size_t)gid*DH + t] / c;
    }
    __syncthreads();
    {
        float acc = fc1b[t];
        const float* w = fc1W + (size_t)t * DH;
#pragma unroll
        for (int k = 0; k < DH; ++k) acc += w[k] * g[k];
        a1[t] = fmaxf(acc, 0.f);
    }
    __syncthreads();
    {
        float acc = fc2b[t];
        const float* w = fc2W + (size_t)t * 128;
#pragma unroll 8
        for (int k = 0; k < 128; ++k) acc += w[k] * a1[k];
        a2[t] = fmaxf(acc, 0.f);
    }
    __syncthreads();
    if (t < 3) {
        float acc = outb[t];
        const float* w = outW + (size_t)t * 128;
#pragma unroll 8
        for (int k = 0; k < 128; ++k) acc += w[k] * a2[k];
        out[(size_t)gid*3 + t] = acc;
    }
}

// ---------------------------------------------------------------------------
extern "C" void kernel_launch(void* const* d_in, const int* in_sizes, int n_in,
                              void* d_out, int out_size, void* d_ws, size_t ws_size,
                              hipStream_t stream)
{
    const float* x     = (const float*)d_in[0];
    const int*   ei    = (const int*)  d_in[1];
    const float* attr  = (const float*)d_in[2];
    const int*   batch = (const int*)  d_in[3];
    const float* preW  = (const float*)d_in[4];
    const float* preb  = (const float*)d_in[5];
    const float* f1W   = (const float*)d_in[6];
    const float* f1b   = (const float*)d_in[7];
    const float* s1W   = (const float*)d_in[8];
    const float* s1b   = (const float*)d_in[9];
    const float* f2W   = (const float*)d_in[10];
    const float* f2b   = (const float*)d_in[11];
    const float* s2W   = (const float*)d_in[12];
    const float* s2b   = (const float*)d_in[13];
    const float* fc1W  = (const float*)d_in[14];
    const float* fc1b  = (const float*)d_in[15];
    const float* fc2W  = (const float*)d_in[16];
    const float* fc2b  = (const float*)d_in[17];
    const float* outW  = (const float*)d_in[18];
    const float* outb  = (const float*)d_in[19];

    const int N = in_sizes[0] / DIN;      // 200000
    const int E = in_sizes[1] / 2;        // 6400000
    const int G = out_size / 3;           // 1024
    const int RS = (N + NR - 1) / NR;     // nodes per src slice
    const int M  = NR * N;                // bucket table size

    const int TB = 256;
    const int nb = (N + TB - 1) / TB;
    const int eb = (E + TB - 1) / TB;
    const int mb = (M + TB - 1) / TB;     // flat-scan blocks
    const int gb = (N * VEC + TB - 1) / TB;

    // ---- CSR-path workspace layout ----
    size_t f_off = 0;
    float* ws = (float*)d_ws;
    float* h    = ws + f_off; f_off += (size_t)N * DH;
    float* D    = ws + f_off; f_off += (size_t)N * REC;
    u32*   Sh   = (u32*)(ws + f_off); f_off += (size_t)N * SHU;
    float* acc  = ws + f_off; f_off += (size_t)N * ACS;
    float* gsum = ws + f_off; f_off += (size_t)G * DH;
    float* gcnt = ws + f_off; f_off += G;
    f_off = (f_off + 15) & ~(size_t)15;
    int* deg    = (int*)(ws + f_off); f_off += M;
    int* bhead  = (int*)(ws + f_off); f_off += M;
    int* bsum   = (int*)(ws + f_off); f_off += mb;
    f_off = (f_off + 15) & ~(size_t)15;
    u32* csrc   = (u32*)(ws + f_off); f_off += E;
    f_off = (f_off + 15) & ~(size_t)15;
    uint2* cattr = (uint2*)(ws + f_off);
    size_t need = (f_off + (size_t)E * 2) * sizeof(float);

    if (need <= ws_size) {
        // ===== slice-synchronized CSR path =====
        zero_misc<<<mb, TB, 0, stream>>>(deg, M, gsum, gcnt, G);
        node_pre_h<<<nb, TB, 0, stream>>>(x, preW, preb, f1W, f1b, s1W, s1b,
                                          h, D, Sh, acc, N);
        hist8<<<eb, TB, 0, stream>>>(ei, deg, E, RS, N);
        scan_block<<<mb, TB, 0, stream>>>(deg, bhead, bsum, M);
        scan_sums_loop<<<1, 1024, 0, stream>>>(bsum, mb);
        scan_add<<<mb, TB, 0, stream>>>(bhead, bsum, M);
        scatter8<<<eb, TB, 0, stream>>>(ei, attr, bhead, csrc, cattr, E, RS, N);

        for (int p = 0; p < NR; ++p)
            gather_slice<<<gb, TB, 0, stream>>>(p, deg, bhead, csrc, cattr,
                                                D, Sh, f1W, s1W, acc, N);
        node_mid_h<<<nb, TB, 0, stream>>>(h, acc, f2W, f2b, s2W, s2b, D, Sh, N);
        for (int p = 0; p < NR; ++p)
            gather_slice<<<gb, TB, 0, stream>>>(p, deg, bhead, csrc, cattr,
                                                D, Sh, f2W, s2W, acc, N);
        node_pool<<<nb, TB, 0, stream>>>(h, acc, batch, gsum, gcnt, N);
        mlp_head<<<G, 128, 0, stream>>>(gsum, gcnt, fc1W, fc1b, fc2W, fc2b,
                                        outW, outb, (float*)d_out, G);
    } else {
        // ===== fallback: fp32 atomic path =====
        size_t o = 0;
        float* fh    = ws + o; o += (size_t)N * DH;
        float* agg   = ws + o; o += (size_t)N * DH;
        float* fD    = ws + o; o += (size_t)N * REC;
        float* fS    = ws + o; o += (size_t)N * REC;
        float* fgsum = ws + o; o += (size_t)G * DH;
        float* fgcnt = ws + o; o += G;

        node_pre_f32<<<nb, TB, 0, stream>>>(x, preW, preb, f1W, f1b, s1W, s1b,
                                            fh, fD, fS, agg, fgsum, fgcnt, N, G);
        edge_pass<<<eb, TB, 0, stream>>>(ei, attr, fD, fS, f1W, s1W, agg, E);
        node_mid<<<nb, TB, 0, stream>>>(fh, agg, f2W, f2b, s2W, s2b, fD, fS, N);
        edge_pass<<<eb, TB, 0, stream>>>(ei, attr, fD, fS, f2W, s2W, agg, E);
        node_post<<<nb, TB, 0, stream>>>(fh, agg, batch, fgsum, fgcnt, N);
        mlp_head<<<G, 128, 0, stream>>>(fgsum, fgcnt, fc1W, fc1b, fc2W, fc2b,
                                        outW, outb, (float*)d_out, G);
    }
}

// Round 9
// 1639.431 us; speedup vs baseline: 1.0550x; 1.0550x over previous
//
#include <hip/hip_runtime.h>
#include <hip/hip_bf16.h>
#include <hip/hip_fp16.h>
#include <math.h>

#define DH 10      // hidden dim
#define DE 3       // edge attr dim
#define DIN 3      // input dim
#define REC 20     // fp32 D record: 20 floats = 80B
#define SHU 12     // fp16 S record stride in uints (24 halves = 48B, 10 used)
#define VEC 4      // lanes cooperating per node in gather
#define SSH 15     // slice shift: 32768 src nodes/slice -> 1.57MB fp16 recs (L2-resident)
#define WGN 1024   // persistent workgroups (4 per CU, all co-resident)
#define MAXNPW 256 // max dst nodes per workgroup (LDS sizing)

typedef unsigned int u32;
typedef float f4v __attribute__((ext_vector_type(4)));
typedef u32   u2v __attribute__((ext_vector_type(2)));

__device__ __forceinline__ u32 pack_h2(float a, float b) {
    union { __half2 h; u32 u; } cv;
    cv.h = __floats2half2_rn(a, b);
    return cv.u;
}
__device__ __forceinline__ float2 unpack_h2(u32 u) {
    union { u32 u; __half2 h; } cv; cv.u = u;
    return __half22float2(cv.h);
}

// ---------------------------------------------------------------------------
// Per-node records. D (fp32, dst side, biases folded). S (fp16 packed).
// ---------------------------------------------------------------------------
__device__ __forceinline__ void compute_records_h(
    const float* __restrict__ hh,
    const float* __restrict__ fW, const float* __restrict__ fb,
    const float* __restrict__ sW, const float* __restrict__ sb,
    float* __restrict__ Dout, u32* __restrict__ Sout)
{
    float fsv[DH], ssv[DH];
#pragma unroll
    for (int j = 0; j < DH; ++j) {
        float fd = fb[j], sd = sb[j], fs = 0.f, ss = 0.f;
#pragma unroll
        for (int k = 0; k < DH; ++k) {
            fd += hh[k] * fW[j*23 + k];
            fs += hh[k] * fW[j*23 + 10 + k];
            sd += hh[k] * sW[j*23 + k];
            ss += hh[k] * sW[j*23 + 10 + k];
        }
        Dout[j]      = fd;
        Dout[DH + j] = sd;
        fsv[j] = fs;
        ssv[j] = ss;
    }
#pragma unroll
    for (int j = 0; j < 5; ++j) {
        Sout[j]     = pack_h2(fsv[2*j], fsv[2*j+1]);
        Sout[5 + j] = pack_h2(ssv[2*j], ssv[2*j+1]);
    }
}

// fp32 variant for the fallback path
__device__ __forceinline__ void compute_records(
    const float* __restrict__ hh,
    const float* __restrict__ fW, const float* __restrict__ fb,
    const float* __restrict__ sW, const float* __restrict__ sb,
    float* __restrict__ Dout, float* __restrict__ Sout)
{
#pragma unroll
    for (int j = 0; j < DH; ++j) {
        float fd = fb[j], sd = sb[j], fs = 0.f, ss = 0.f;
#pragma unroll
        for (int k = 0; k < DH; ++k) {
            fd += hh[k] * fW[j*23 + k];
            fs += hh[k] * fW[j*23 + 10 + k];
            sd += hh[k] * sW[j*23 + k];
            ss += hh[k] * sW[j*23 + 10 + k];
        }
        Dout[j]      = fd;
        Dout[DH + j] = sd;
        Sout[j]      = fs;
        Sout[DH + j] = ss;
    }
}

// ---------------------------------------------------------------------------
__global__ void zero_misc(int* __restrict__ deg, int M,
                          float* __restrict__ gsum, float* __restrict__ gcnt, int G)
{
    int i = blockIdx.x * blockDim.x + threadIdx.x;
    if (i < M) deg[i] = 0;
    if (i < G * DH) gsum[i] = 0.f;
    if (i < G) gcnt[i] = 0.f;
}

// ---------------------------------------------------------------------------
// P0: h0 = relu(x@preW.T+preb); layer-1 records
// ---------------------------------------------------------------------------
__global__ void node_pre_h(const float* __restrict__ x,
                           const float* __restrict__ preW, const float* __restrict__ preb,
                           const float* __restrict__ fW, const float* __restrict__ fb,
                           const float* __restrict__ sW, const float* __restrict__ sb,
                           float* __restrict__ h, float* __restrict__ D, u32* __restrict__ Sh,
                           int N)
{
    __shared__ float lpW[30], lpb[10], lfW[230], lfb[10], lsW[230], lsb[10];
    for (int i = threadIdx.x; i < 30;  i += blockDim.x) lpW[i] = preW[i];
    for (int i = threadIdx.x; i < 10;  i += blockDim.x) { lpb[i] = preb[i]; lfb[i] = fb[i]; lsb[i] = sb[i]; }
    for (int i = threadIdx.x; i < 230; i += blockDim.x) { lfW[i] = fW[i]; lsW[i] = sW[i]; }
    __syncthreads();

    int n = blockIdx.x * blockDim.x + threadIdx.x;
    if (n >= N) return;

    float x0 = x[(size_t)n*3], x1 = x[(size_t)n*3+1], x2 = x[(size_t)n*3+2];
    float hh[DH];
#pragma unroll
    for (int j = 0; j < DH; ++j)
        hh[j] = fmaxf(lpb[j] + x0*lpW[j*3] + x1*lpW[j*3+1] + x2*lpW[j*3+2], 0.f);

    float* hp = h + (size_t)n * DH;
#pragma unroll
    for (int j = 0; j < DH; ++j) hp[j] = hh[j];

    compute_records_h(hh, lfW, lfb, lsW, lsb, D + (size_t)n*REC, Sh + (size_t)n*SHU);
}

// ---------------------------------------------------------------------------
// Bucket build (slice-major [p][n]): hist -> flat scan -> packed 8B scatter
// ---------------------------------------------------------------------------
__global__ void hist_k(const int* __restrict__ ei, int* __restrict__ deg, int E, int N)
{
    int e = blockIdx.x * blockDim.x + threadIdx.x;
    if (e >= E) return;
    int src = __builtin_nontemporal_load(ei + e);
    int dst = __builtin_nontemporal_load(ei + (size_t)E + e);
    int r = src >> SSH;
    atomicAdd(&deg[(size_t)r * N + dst], 1);
}

__global__ void scan_block(const int* __restrict__ deg, int* __restrict__ excl,
                           int* __restrict__ bsum, int M)
{
    __shared__ int s[256];
    int tid = threadIdx.x;
    int i = blockIdx.x * 256 + tid;
    int v = (i < M) ? deg[i] : 0;
    s[tid] = v;
    __syncthreads();
#pragma unroll
    for (int off = 1; off < 256; off <<= 1) {
        int t = (tid >= off) ? s[tid - off] : 0;
        __syncthreads();
        if (tid >= off) s[tid] += t;
        __syncthreads();
    }
    if (i < M) excl[i] = s[tid] - v;
    if (tid == 255) bsum[blockIdx.x] = s[255];
}

__global__ void scan_sums_loop(int* __restrict__ bsum, int B)   // exclusive, in place
{
    __shared__ int s[1024];
    __shared__ int carry_s;
    int tid = threadIdx.x;
    if (tid == 0) carry_s = 0;
    __syncthreads();
    for (int base = 0; base < B; base += 1024) {
        int i = base + tid;
        int v = (i < B) ? bsum[i] : 0;
        s[tid] = v;
        __syncthreads();
#pragma unroll
        for (int off = 1; off < 1024; off <<= 1) {
            int t = (tid >= off) ? s[tid - off] : 0;
            __syncthreads();
            if (tid >= off) s[tid] += t;
            __syncthreads();
        }
        int carry = carry_s;
        if (i < B) bsum[i] = carry + s[tid] - v;
        __syncthreads();
        if (tid == 0) carry_s = carry + s[1023];
        __syncthreads();
    }
}

__global__ void scan_add(int* __restrict__ bhead, const int* __restrict__ bsum, int M)
{
    int i = blockIdx.x * blockDim.x + threadIdx.x;
    if (i < M) bhead[i] += bsum[i >> 8];
}

// one 8B store per edge: {src(18b) | a2q(14b), h2(a0,a1)}
__global__ void scatter_pack(const int* __restrict__ ei, const float* __restrict__ attr,
                             int* __restrict__ bhead, uint2* __restrict__ csr, int E, int N)
{
    int e = blockIdx.x * blockDim.x + threadIdx.x;
    if (e >= E) return;
    int src = __builtin_nontemporal_load(ei + e);
    int dst = __builtin_nontemporal_load(ei + (size_t)E + e);
    float a0 = __builtin_nontemporal_load(attr + (size_t)e * DE);
    float a1 = __builtin_nontemporal_load(attr + (size_t)e * DE + 1);
    float a2 = __builtin_nontemporal_load(attr + (size_t)e * DE + 2);
    int r = src >> SSH;
    int pos = atomicAdd(&bhead[(size_t)r * N + dst], 1);
    u32 a2q = (u32)(fminf(fmaxf(a2, 0.f), 1.0f) * 16383.0f + 0.5f);
    csr[pos] = make_uint2((u32)src | (a2q << 18), pack_h2(a0, a1));
}

// ---------------------------------------------------------------------------
// Persistent gather: each wg owns npw dst nodes; drec+acc staged in LDS; walks
// src slices in lockstep (all wgs co-resident) so the slice's S-records stay
// L2-resident; edge stream is contiguous per (wg, slice) and nontemporal.
// ---------------------------------------------------------------------------
__global__ __launch_bounds__(256, 4) void gather_persist(
    const int* __restrict__ deg, const int* __restrict__ bhead,
    const uint2* __restrict__ csr,
    const float* __restrict__ D, const u32* __restrict__ ShU,
    const float* __restrict__ Wf, const float* __restrict__ Ws,
    float* __restrict__ accg, int N, int nr, int npw)
{
    __shared__ float s_drec[MAXNPW * REC];   // 20 KB
    __shared__ float s_acc[MAXNPW * DH];     // 10 KB

    int base = blockIdx.x * npw;
    if (base >= N) return;
    int cn = N - base; if (cn > npw) cn = npw;

    for (int i = threadIdx.x; i < cn * REC; i += 256)
        s_drec[i] = __builtin_nontemporal_load(D + (size_t)base * REC + i);
    for (int i = threadIdx.x; i < cn * DH; i += 256)
        s_acc[i] = 0.f;

    float wf[30], wsr[30];   // wave-uniform -> compiler puts in SGPRs
#pragma unroll
    for (int i = 0; i < 30; ++i) {
        int j = i / 3, t = i % 3;
        wf[i]  = Wf[j*23 + 20 + t];
        wsr[i] = Ws[j*23 + 20 + t];
    }
    __syncthreads();

    int g   = threadIdx.x >> 2;       // lane-group (node within chunk)
    int sub = threadIdx.x & (VEC - 1);
    int nchunk = (cn + 63) >> 6;

    for (int p = 0; p < nr; ++p) {
        for (int c = 0; c < nchunk; ++c) {
            int nl = (c << 6) + g;
            if (nl < cn) {
                size_t idx = (size_t)p * N + (base + nl);
                int end = bhead[idx];
                int cnt = deg[idx];

                float partial[DH];
#pragma unroll
                for (int j = 0; j < DH; ++j) partial[j] = 0.f;

                if (cnt > 0) {
                    float dr[REC];
#pragma unroll
                    for (int j = 0; j < REC; ++j) dr[j] = s_drec[nl*REC + j];

                    for (int q = end - cnt + sub; q < end; q += VEC) {
                        u2v c2 = __builtin_nontemporal_load(((const u2v*)csr) + q);
                        u32 w0 = c2.x;
                        int src = (int)(w0 & 0x3FFFFu);
                        float a2 = (float)(w0 >> 18) * (1.0f / 16383.0f);
                        float2 a01 = unpack_h2(c2.y);
                        float a0 = a01.x, a1 = a01.y;

                        const uint4* sp = (const uint4*)(ShU + (size_t)src * SHU);
                        uint4 A = sp[0];
                        uint4 B = sp[1];
                        uint2 C = *(const uint2*)(sp + 2);
                        u32 u[10] = {A.x, A.y, A.z, A.w, B.x, B.y, B.z, B.w, C.x, C.y};
                        float s[20];
#pragma unroll
                        for (int i = 0; i < 10; ++i) {
                            float2 f = unpack_h2(u[i]);
                            s[2*i] = f.x; s[2*i+1] = f.y;
                        }
#pragma unroll
                        for (int j = 0; j < DH; ++j) {
                            float pf = dr[j]      + s[j]      + a0*wf[j*3]  + a1*wf[j*3+1]  + a2*wf[j*3+2];
                            float ps = dr[DH + j] + s[DH + j] + a0*wsr[j*3] + a1*wsr[j*3+1] + a2*wsr[j*3+2];
                            float sg  = __builtin_amdgcn_rcpf(1.0f + __expf(-pf));           // sigmoid
                            float sp2 = fmaxf(ps, 0.f) + __logf(1.0f + __expf(-fabsf(ps)));  // softplus
                            partial[j] += sg * sp2;
                        }
                    }
                }
#pragma unroll
                for (int j = 0; j < DH; ++j) {
                    partial[j] += __shfl_xor(partial[j], 1);
                    partial[j] += __shfl_xor(partial[j], 2);
                }
                if (sub == 0 && cnt > 0) {
#pragma unroll
                    for (int j = 0; j < DH; ++j) s_acc[nl*DH + j] += partial[j];
                }
            }
        }
        __syncthreads();   // keep the wg's waves slice-aligned
    }

    for (int i = threadIdx.x; i < cn * DH; i += 256)
        accg[(size_t)base * DH + i] = s_acc[i];
}

// ---------------------------------------------------------------------------
// Layer-1 epilogue: h = relu(h + acc); records for layer 2
// ---------------------------------------------------------------------------
__global__ void node_mid_h(float* __restrict__ h, const float* __restrict__ acc,
                           const float* __restrict__ fW, const float* __restrict__ fb,
                           const float* __restrict__ sW, const float* __restrict__ sb,
                           float* __restrict__ D, u32* __restrict__ Sh, int N)
{
    __shared__ float lfW[230], lfb[10], lsW[230], lsb[10];
    for (int i = threadIdx.x; i < 230; i += blockDim.x) { lfW[i] = fW[i]; lsW[i] = sW[i]; }
    for (int i = threadIdx.x; i < 10;  i += blockDim.x) { lfb[i] = fb[i]; lsb[i] = sb[i]; }
    __syncthreads();
    int n = blockIdx.x * blockDim.x + threadIdx.x;
    if (n >= N) return;
    float* hp = h + (size_t)n * DH;
    const float* ap = acc + (size_t)n * DH;
    float hh[DH];
#pragma unroll
    for (int j = 0; j < DH; ++j) {
        hh[j] = fmaxf(hp[j] + ap[j], 0.f);
        hp[j] = hh[j];
    }
    compute_records_h(hh, lfW, lfb, lsW, lsb, D + (size_t)n*REC, Sh + (size_t)n*SHU);
}

// ---------------------------------------------------------------------------
// Layer-2 epilogue: pool relu(h + acc) into gsum/gcnt
// ---------------------------------------------------------------------------
__global__ void node_pool(const float* __restrict__ h, const float* __restrict__ acc,
                          const int* __restrict__ batch,
                          float* __restrict__ gsum, float* __restrict__ gcnt, int N)
{
    int n = blockIdx.x * blockDim.x + threadIdx.x;
    if (n >= N) return;
    int b = batch[n];
    const float* hp = h + (size_t)n * DH;
    const float* ap = acc + (size_t)n * DH;
    float* gp = gsum + (size_t)b * DH;
#pragma unroll
    for (int j = 0; j < DH; ++j)
        atomicAdd(gp + j, fmaxf(hp[j] + ap[j], 0.f));
    atomicAdd(gcnt + b, 1.f);
}

// ---------------------------------------------------------------------------
// Fallback path kernels (fp32 atomic path; used only if ws too small)
// ---------------------------------------------------------------------------
__global__ void node_pre_f32(const float* __restrict__ x,
                             const float* __restrict__ preW, const float* __restrict__ preb,
                             const float* __restrict__ fW, const float* __restrict__ fb,
                             const float* __restrict__ sW, const float* __restrict__ sb,
                             float* __restrict__ h, float* __restrict__ D, float* __restrict__ S,
                             float* __restrict__ agg,
                             float* __restrict__ gsum, float* __restrict__ gcnt, int N, int G)
{
    __shared__ float lpW[30], lpb[10], lfW[230], lfb[10], lsW[230], lsb[10];
    for (int i = threadIdx.x; i < 30;  i += blockDim.x) lpW[i] = preW[i];
    for (int i = threadIdx.x; i < 10;  i += blockDim.x) { lpb[i] = preb[i]; lfb[i] = fb[i]; lsb[i] = sb[i]; }
    for (int i = threadIdx.x; i < 230; i += blockDim.x) { lfW[i] = fW[i]; lsW[i] = sW[i]; }
    __syncthreads();
    int n = blockIdx.x * blockDim.x + threadIdx.x;
    if (n < G * DH) gsum[n] = 0.f;
    if (n < G)      gcnt[n] = 0.f;
    if (n >= N) return;
    float x0 = x[(size_t)n*3], x1 = x[(size_t)n*3+1], x2 = x[(size_t)n*3+2];
    float hh[DH];
#pragma unroll
    for (int j = 0; j < DH; ++j)
        hh[j] = fmaxf(lpb[j] + x0*lpW[j*3] + x1*lpW[j*3+1] + x2*lpW[j*3+2], 0.f);
    float* hp = h + (size_t)n * DH;
    float* ap = agg + (size_t)n * DH;
#pragma unroll
    for (int j = 0; j < DH; ++j) { hp[j] = hh[j]; ap[j] = 0.f; }
    compute_records(hh, lfW, lfb, lsW, lsb, D + (size_t)n*REC, S + (size_t)n*REC);
}

__global__ void edge_pass(const int* __restrict__ ei, const float* __restrict__ attr,
                          const float* __restrict__ D, const float* __restrict__ S,
                          const float* __restrict__ Wf, const float* __restrict__ Ws,
                          float* __restrict__ agg, int E)
{
    __shared__ float wfe[30], wse[30];
    if (threadIdx.x < 30) {
        int j = threadIdx.x / 3, t = threadIdx.x % 3;
        wfe[threadIdx.x] = Wf[j*23 + 20 + t];
        wse[threadIdx.x] = Ws[j*23 + 20 + t];
    }
    __syncthreads();
    int e = blockIdx.x * blockDim.x + threadIdx.x;
    if (e >= E) return;
    int src = ei[e];
    int dst = ei[(size_t)E + e];
    const float* eap = attr + (size_t)e * DE;
    float ea0 = eap[0], ea1 = eap[1], ea2 = eap[2];
    float drec[REC], srec[REC];
    const float4* Dp = (const float4*)(D + (size_t)dst * REC);
    const float4* Sp = (const float4*)(S + (size_t)src * REC);
#pragma unroll
    for (int i = 0; i < 5; ++i) { ((float4*)drec)[i] = Dp[i]; ((float4*)srec)[i] = Sp[i]; }
    float* ap = agg + (size_t)dst * DH;
#pragma unroll
    for (int j = 0; j < DH; ++j) {
        float pf = drec[j]      + srec[j]      + ea0*wfe[j*3] + ea1*wfe[j*3+1] + ea2*wfe[j*3+2];
        float ps = drec[DH + j] + srec[DH + j] + ea0*wse[j*3] + ea1*wse[j*3+1] + ea2*wse[j*3+2];
        float sg = 1.0f / (1.0f + __expf(-pf));
        float sp = fmaxf(ps, 0.f) + log1pf(__expf(-fabsf(ps)));
        atomicAdd(ap + j, sg * sp);
    }
}

__global__ void node_mid(float* __restrict__ h, float* __restrict__ agg,
                         const float* __restrict__ fW, const float* __restrict__ fb,
                         const float* __restrict__ sW, const float* __restrict__ sb,
                         float* __restrict__ D, float* __restrict__ S, int N)
{
    __shared__ float lfW[230], lfb[10], lsW[230], lsb[10];
    for (int i = threadIdx.x; i < 230; i += blockDim.x) { lfW[i] = fW[i]; lsW[i] = sW[i]; }
    for (int i = threadIdx.x; i < 10;  i += blockDim.x) { lfb[i] = fb[i]; lsb[i] = sb[i]; }
    __syncthreads();
    int n = blockIdx.x * blockDim.x + threadIdx.x;
    if (n >= N) return;
    float* hp = h + (size_t)n * DH;
    float* ap = agg + (size_t)n * DH;
    float hh[DH];
#pragma unroll
    for (int j = 0; j < DH; ++j) {
        hh[j] = fmaxf(hp[j] + ap[j], 0.f);
        hp[j] = hh[j];
        ap[j] = 0.f;
    }
    compute_records(hh, lfW, lfb, lsW, lsb, D + (size_t)n*REC, S + (size_t)n*REC);
}

__global__ void node_post(const float* __restrict__ h, const float* __restrict__ agg,
                          const int* __restrict__ batch,
                          float* __restrict__ gsum, float* __restrict__ gcnt, int N)
{
    int n = blockIdx.x * blockDim.x + threadIdx.x;
    if (n >= N) return;
    int b = batch[n];
    const float* hp = h + (size_t)n * DH;
    const float* ap = agg + (size_t)n * DH;
    float* gp = gsum + (size_t)b * DH;
#pragma unroll
    for (int j = 0; j < DH; ++j)
        atomicAdd(gp + j, fmaxf(hp[j] + ap[j], 0.f));
    atomicAdd(gcnt + b, 1.f);
}

// ---------------------------------------------------------------------------
// MLP head: one block (128 threads) per graph.
// ---------------------------------------------------------------------------
__global__ void mlp_head(const float* __restrict__ gsum, const float* __restrict__ gcnt,
                         const float* __restrict__ fc1W, const float* __restrict__ fc1b,
                         const float* __restrict__ fc2W, const float* __restrict__ fc2b,
                         const float* __restrict__ outW, const float* __restrict__ outb,
                         float* __restrict__ out, int G)
{
    __shared__ float g[DH], a1[128], a2[128];
    int gid = blockIdx.x;
    int t = threadIdx.x;
    if (t < DH) {
        float c = fmaxf(gcnt[gid], 1.0f);
        g[t] = gsum[(size_t)gid*DH + t] / c;
    }
    __syncthreads();
    {
        float acc = fc1b[t];
        const float* w = fc1W + (size_t)t * DH;
#pragma unroll
        for (int k = 0; k < DH; ++k) acc += w[k] * g[k];
        a1[t] = fmaxf(acc, 0.f);
    }
    __syncthreads();
    {
        float acc = fc2b[t];
        const float* w = fc2W + (size_t)t * 128;
#pragma unroll 8
        for (int k = 0; k < 128; ++k) acc += w[k] * a1[k];
        a2[t] = fmaxf(acc, 0.f);
    }
    __syncthreads();
    if (t < 3) {
        float acc = outb[t];
        const float* w = outW + (size_t)t * 128;
#pragma unroll 8
        for (int k = 0; k < 128; ++k) acc += w[k] * a2[k];
        out[(size_t)gid*3 + t] = acc;
    }
}

// ---------------------------------------------------------------------------
extern "C" void kernel_launch(void* const* d_in, const int* in_sizes, int n_in,
                              void* d_out, int out_size, void* d_ws, size_t ws_size,
                              hipStream_t stream)
{
    const float* x     = (const float*)d_in[0];
    const int*   ei    = (const int*)  d_in[1];
    const float* attr  = (const float*)d_in[2];
    const int*   batch = (const int*)  d_in[3];
    const float* preW  = (const float*)d_in[4];
    const float* preb  = (const float*)d_in[5];
    const float* f1W   = (const float*)d_in[6];
    const float* f1b   = (const float*)d_in[7];
    const float* s1W   = (const float*)d_in[8];
    const float* s1b   = (const float*)d_in[9];
    const float* f2W   = (const float*)d_in[10];
    const float* f2b   = (const float*)d_in[11];
    const float* s2W   = (const float*)d_in[12];
    const float* s2b   = (const float*)d_in[13];
    const float* fc1W  = (const float*)d_in[14];
    const float* fc1b  = (const float*)d_in[15];
    const float* fc2W  = (const float*)d_in[16];
    const float* fc2b  = (const float*)d_in[17];
    const float* outW  = (const float*)d_in[18];
    const float* outb  = (const float*)d_in[19];

    const int N = in_sizes[0] / DIN;          // 200000
    const int E = in_sizes[1] / 2;            // 6400000
    const int G = out_size / 3;               // 1024
    const int RS = 1 << SSH;                  // 32768 nodes per src slice
    const int nr = (N + RS - 1) >> SSH;       // 7 slices
    const int M  = nr * N;                    // bucket table size
    const int npw = (N + WGN - 1) / WGN;      // 196 dst nodes per persistent wg

    const int TB = 256;
    const int nb = (N + TB - 1) / TB;
    const int eb = (E + TB - 1) / TB;
    const int mb = (M + TB - 1) / TB;

    // ---- workspace layout ----
    size_t f_off = 0;
    float* ws = (float*)d_ws;
    float* h    = ws + f_off; f_off += (size_t)N * DH;
    float* D    = ws + f_off; f_off += (size_t)N * REC;
    u32*   Sh   = (u32*)(ws + f_off); f_off += (size_t)N * SHU;
    float* acc  = ws + f_off; f_off += (size_t)N * DH;
    float* gsum = ws + f_off; f_off += (size_t)G * DH;
    float* gcnt = ws + f_off; f_off += G;
    f_off = (f_off + 15) & ~(size_t)15;
    int* deg    = (int*)(ws + f_off); f_off += M;
    int* bhead  = (int*)(ws + f_off); f_off += M;
    int* bsum   = (int*)(ws + f_off); f_off += mb;
    f_off = (f_off + 15) & ~(size_t)15;
    uint2* csr  = (uint2*)(ws + f_off);
    size_t need = (f_off + (size_t)E * 2) * sizeof(float);   // ~106 MB

    if (need <= ws_size && npw <= MAXNPW && N < (1 << 18)) {
        // ===== persistent slice-walk path =====
        zero_misc<<<mb, TB, 0, stream>>>(deg, M, gsum, gcnt, G);
        node_pre_h<<<nb, TB, 0, stream>>>(x, preW, preb, f1W, f1b, s1W, s1b,
                                          h, D, Sh, N);
        hist_k<<<eb, TB, 0, stream>>>(ei, deg, E, N);
        scan_block<<<mb, TB, 0, stream>>>(deg, bhead, bsum, M);
        scan_sums_loop<<<1, 1024, 0, stream>>>(bsum, mb);
        scan_add<<<mb, TB, 0, stream>>>(bhead, bsum, M);
        scatter_pack<<<eb, TB, 0, stream>>>(ei, attr, bhead, csr, E, N);

        gather_persist<<<WGN, 256, 0, stream>>>(deg, bhead, csr, D, Sh,
                                                f1W, s1W, acc, N, nr, npw);
        node_mid_h<<<nb, TB, 0, stream>>>(h, acc, f2W, f2b, s2W, s2b, D, Sh, N);
        gather_persist<<<WGN, 256, 0, stream>>>(deg, bhead, csr, D, Sh,
                                                f2W, s2W, acc, N, nr, npw);
        node_pool<<<nb, TB, 0, stream>>>(h, acc, batch, gsum, gcnt, N);
        mlp_head<<<G, 128, 0, stream>>>(gsum, gcnt, fc1W, fc1b, fc2W, fc2b,
                                        outW, outb, (float*)d_out, G);
    } else {
        // ===== fallback: fp32 atomic path =====
        size_t o = 0;
        float* fh    = ws + o; o += (size_t)N * DH;
        float* agg   = ws + o; o += (size_t)N * DH;
        float* fD    = ws + o; o += (size_t)N * REC;
        float* fS    = ws + o; o += (size_t)N * REC;
        float* fgsum = ws + o; o += (size_t)G * DH;
        float* fgcnt = ws + o; o += G;

        node_pre_f32<<<nb, TB, 0, stream>>>(x, preW, preb, f1W, f1b, s1W, s1b,
                                            fh, fD, fS, agg, fgsum, fgcnt, N, G);
        edge_pass<<<eb, TB, 0, stream>>>(ei, attr, fD, fS, f1W, s1W, agg, E);
        node_mid<<<nb, TB, 0, stream>>>(fh, agg, f2W, f2b, s2W, s2b, fD, fS, N);
        edge_pass<<<eb, TB, 0, stream>>>(ei, attr, fD, fS, f2W, s2W, agg, E);
        node_post<<<nb, TB, 0, stream>>>(fh, agg, batch, fgsum, fgcnt, N);
        mlp_head<<<G, 128, 0, stream>>>(fgsum, fgcnt, fc1W, fc1b, fc2W, fc2b,
                                        outW, outb, (float*)d_out, G);
    }
}